// Round 2
// baseline (78.514 us; speedup 1.0000x reference)
//
#include <hip/hip_runtime.h>

#define NG 256                  // 16 (b,s)-groups * 16 classes
#define AGG_FLOATS (10 * NG)    // count, msum, esum[8]  (SoA: [field][g], g = gi*16+c)
#define PAR_MAIN (NG * 12)      // per (c*16+gi): w[8]=2*inv*cent, inv, c2*inv, bce_scale, sigma
#define PAR_TOTAL (PAR_MAIN + 16)  // + smooth_scale[gi]

__global__ void k_zero(float* __restrict__ agg, float* __restrict__ out) {
    int t = blockIdx.x * blockDim.x + threadIdx.x;
    if (t < AGG_FLOATS) agg[t] = 0.0f;
    if (t == 0) out[0] = 0.0f;
}

__global__ void k_agg(const float* __restrict__ emb, const float* __restrict__ marg,
                      const int* __restrict__ slab, const int* __restrict__ clab,
                      const int* __restrict__ bidx, float* __restrict__ agg, int n) {
    __shared__ float sa[AGG_FLOATS];
    for (int t = threadIdx.x; t < AGG_FLOATS; t += blockDim.x) sa[t] = 0.0f;
    __syncthreads();
    int stride = gridDim.x * blockDim.x;
    for (int i = blockIdx.x * blockDim.x + threadIdx.x; i < n; i += stride) {
        int s = slab[i];
        if (s >= 4) continue;
        int g = ((bidx[i] * 4 + s) << 4) | clab[i];
        const float4* e4 = (const float4*)(emb + (size_t)i * 8);
        float4 e0 = e4[0], e1 = e4[1];
        atomicAdd(&sa[g],        1.0f);
        atomicAdd(&sa[NG + g],   marg[i]);
        atomicAdd(&sa[2*NG + g], e0.x);
        atomicAdd(&sa[3*NG + g], e0.y);
        atomicAdd(&sa[4*NG + g], e0.z);
        atomicAdd(&sa[5*NG + g], e0.w);
        atomicAdd(&sa[6*NG + g], e1.x);
        atomicAdd(&sa[7*NG + g], e1.y);
        atomicAdd(&sa[8*NG + g], e1.z);
        atomicAdd(&sa[9*NG + g], e1.w);
    }
    __syncthreads();
    for (int t = threadIdx.x; t < AGG_FLOATS; t += blockDim.x) {
        float v = sa[t];
        if (v != 0.0f) atomicAdd(&agg[t], v);
    }
}

__global__ void k_final(const float* __restrict__ agg, float* __restrict__ par) {
    int g = threadIdx.x;        // g = gi*16 + c ; 16 consecutive lanes = one (b,s)
    int gi = g >> 4, c = g & 15;
    float count = agg[g];
    float msum  = agg[NG + g];
    bool present = count > 0.0f;
    float cnt = present ? count : 1.0f;
    float nsub = count, ncl = present ? 1.0f : 0.0f;
    #pragma unroll
    for (int m = 1; m < 16; m <<= 1) {   // stays inside the 16-lane group
        nsub += __shfl_xor(nsub, m);
        ncl  += __shfl_xor(ncl, m);
    }
    nsub = fmaxf(nsub, 1.0f);
    ncl  = fmaxf(ncl, 1.0f);
    float sigma = msum / cnt;
    float inv = 1.0f / (2.0f * sigma * sigma + 1e-8f);
    float c2 = 0.0f;
    float cd[8];
    #pragma unroll
    for (int d = 0; d < 8; ++d) {
        cd[d] = agg[(2 + d) * NG + g] / cnt;
        c2 += cd[d] * cd[d];
    }
    float* p = par + (c * 16 + gi) * 12;   // class-major: spreads banks over gi
    #pragma unroll
    for (int d = 0; d < 8; ++d) p[d] = 2.0f * inv * cd[d];
    p[8]  = inv;
    p[9]  = c2 * inv;
    p[10] = present ? 1.0f / (16.0f * nsub * ncl) : 0.0f;
    p[11] = sigma;
    if (c == 0) par[PAR_MAIN + gi] = 1.0f / (16.0f * ncl);
}

__global__ void k_main(const float* __restrict__ emb, const float* __restrict__ marg,
                       const int* __restrict__ slab, const int* __restrict__ clab,
                       const int* __restrict__ bidx, const float* __restrict__ par,
                       float* __restrict__ out, int n) {
    __shared__ float sp[PAR_TOTAL];
    __shared__ float wsum[4];
    for (int t = threadIdx.x; t < PAR_TOTAL; t += blockDim.x) sp[t] = par[t];
    __syncthreads();
    float acc = 0.0f;
    int stride = gridDim.x * blockDim.x;
    for (int i = blockIdx.x * blockDim.x + threadIdx.x; i < n; i += stride) {
        int s = slab[i];
        if (s >= 4) continue;
        int gi = bidx[i] * 4 + s;
        int cl = clab[i];
        const float4* e4 = (const float4*)(emb + (size_t)i * 8);
        float4 ea = e4[0], eb = e4[1];
        float e2 = ea.x*ea.x + ea.y*ea.y + ea.z*ea.z + ea.w*ea.w
                 + eb.x*eb.x + eb.y*eb.y + eb.z*eb.z + eb.w*eb.w;
        float m = marg[i];
        float lsum = 0.0f;
        float sig_cl = 0.0f;
        #pragma unroll 4
        for (int c = 0; c < 16; ++c) {
            const float4* q = (const float4*)(sp + (c * 16 + gi) * 12);
            float4 w0 = q[0], w1 = q[1], w2 = q[2];
            float dot = w0.x*ea.x + w0.y*ea.y + w0.z*ea.z + w0.w*ea.w
                      + w1.x*eb.x + w1.y*eb.y + w1.z*eb.z + w1.w*eb.w;
            float z = fmaf(e2, w2.x, w2.y) - dot;       // dist * inv_denom
            float p = __expf(-z);
            // BCE collapses: hit -> -log(clamp(e^-z)) = clamp(z); miss -> -log(1-pc)
            float zc = fminf(fmaxf(z, 1.0000005e-6f), 13.815511f);
            float ln = -__logf(fmaxf(1.0f - p, 1e-6f));
            bool hit = (c == cl);
            lsum += (hit ? zc : ln) * w2.z;
            if (hit) sig_cl = w2.w;
        }
        float dm = m - sig_cl;
        acc += lsum + dm * dm * sp[PAR_MAIN + gi];
    }
    #pragma unroll
    for (int off = 32; off >= 1; off >>= 1) acc += __shfl_down(acc, off);
    int wid = threadIdx.x >> 6, lane = threadIdx.x & 63;
    if (lane == 0) wsum[wid] = acc;
    __syncthreads();
    if (threadIdx.x == 0) {
        float t = 0.0f;
        int nw = blockDim.x >> 6;
        for (int w = 0; w < nw; ++w) t += wsum[w];
        atomicAdd(out, t);
    }
}

extern "C" void kernel_launch(void* const* d_in, const int* in_sizes, int n_in,
                              void* d_out, int out_size, void* d_ws, size_t ws_size,
                              hipStream_t stream) {
    const float* emb  = (const float*)d_in[0];
    const float* marg = (const float*)d_in[1];
    const int*   slab = (const int*)d_in[2];
    const int*   clab = (const int*)d_in[3];
    const int*   bidx = (const int*)d_in[4];
    float* out = (float*)d_out;
    int n = in_sizes[2];

    float* agg = (float*)d_ws;
    float* par = agg + AGG_FLOATS;

    k_zero <<<(AGG_FLOATS + 255) / 256, 256, 0, stream>>>(agg, out);
    k_agg  <<<512, 512, 0, stream>>>(emb, marg, slab, clab, bidx, agg, n);
    k_final<<<1, 256, 0, stream>>>(agg, par);
    k_main <<<2048, 256, 0, stream>>>(emb, marg, slab, clab, bidx, par, out, n);
}